// Round 24
// baseline (243.682 us; speedup 1.0000x reference)
//
#include <hip/hip_runtime.h>
#include <math.h>

// Problem constants
#define B_  4
#define S_  2048
#define D_  1024
#define H_  16
#define DK_ 64

typedef __bf16 bf16x8 __attribute__((ext_vector_type(8)));
typedef float  f32x4  __attribute__((ext_vector_type(4)));

__device__ __forceinline__ unsigned short f2bf(float f) {
  unsigned int u = __builtin_bit_cast(unsigned int, f);
  u += 0x7fffu + ((u >> 16) & 1u);   // round to nearest even
  return (unsigned short)(u >> 16);
}

__device__ __forceinline__ unsigned short bfbits(float f) {
  __bf16 h = (__bf16)f;              // native cvt (RNE)
  return __builtin_bit_cast(unsigned short, h);
}

__device__ __forceinline__ f32x4 mfma16(bf16x8 a, bf16x8 b, f32x4 c) {
  return __builtin_amdgcn_mfma_f32_16x16x32_bf16(a, b, c, 0, 0, 0);
}

__device__ __forceinline__ void gl_lds16(const unsigned short* g, unsigned short* l) {
  __builtin_amdgcn_global_load_lds(
      (const __attribute__((address_space(1))) void*)g,
      (__attribute__((address_space(3))) void*)l, 16, 0, 0);
}

// ---------------------------------------------------------------- casts (one launch)
__global__ void SAA_cast_all(const float* __restrict__ x,
                             const float* __restrict__ s1, const float* __restrict__ s2,
                             const float* __restrict__ s3, const float* __restrict__ s4,
                             unsigned short* __restrict__ dx,
                             unsigned short* __restrict__ d1, unsigned short* __restrict__ d2,
                             unsigned short* __restrict__ d3, unsigned short* __restrict__ d4)
{
  const int y = blockIdx.y;
  const float* src = (y == 0) ? x : (y == 1) ? s1 : (y == 2) ? s2 : (y == 3) ? s3 : s4;
  unsigned short* dst = (y == 0) ? dx : (y == 1) ? d1 : (y == 2) ? d2 : (y == 3) ? d3 : d4;
  const int n4 = (y == 0) ? (B_ * S_ * D_) / 4 : (D_ * D_) / 4;
  int i = blockIdx.x * blockDim.x + threadIdx.x;
  int stride = gridDim.x * blockDim.x;
  for (; i < n4; i += stride) {
    float4 v = reinterpret_cast<const float4*>(src)[i];
    ushort4 o;
    o.x = f2bf(v.x); o.y = f2bf(v.y); o.z = f2bf(v.z); o.w = f2bf(v.w);
    reinterpret_cast<ushort4*>(dst)[i] = o;
  }
}

// ---------------------------------------------------------------- fused QKV GEMM
// BM=256, BK=64 (was 32): same 104 B/MFMA but HALF the barrier-drain count
// (16 vs 32). Out-GEMM evidence: per-barrier vmcnt(0) tail is a fixed cost --
// out-GEMM stages 295 MB through 16 drains/block at >=13 TB/s vs QKV's 7 at
// 32 drains. LDS = sA 2x32KB + sB 2x3x16KB = 160 KB (full pool, 1 block/CU).
// 10 gl_lds/thread/tile. Chunk-XOR swizzle for 128B rows (chunk ^= row&7,
// r9/r13-verified 0 conflicts). Prefetch-dbuf. XCD-aware grid (n0 = bid&7).
// K rows pre-scaled by 0.125*log2(e)*rw[s]; V stored KEY-PERMUTED (matches
// attention's P layout).
__global__ __launch_bounds__(512)
void SAA_gemm_qkv(const unsigned short* __restrict__ Xb,
                  const unsigned short* __restrict__ Wqb,
                  const unsigned short* __restrict__ Wkb,
                  const unsigned short* __restrict__ Wvb,
                  const float* __restrict__ bq,
                  const float* __restrict__ bk,
                  const float* __restrict__ bv,
                  const float* __restrict__ rw,
                  unsigned short* __restrict__ Qo,
                  unsigned short* __restrict__ Ko,
                  unsigned short* __restrict__ Vto)
{
  const int K = D_;
  __shared__ __attribute__((aligned(16))) unsigned short smem[81920];   // 160 KB
#define sAp(sl)     (smem + (sl) * 16384)                      // 256x64 each (32 KB)
#define sBp(sl, m)  (smem + 32768 + ((sl) * 3 + (m)) * 8192)   // 128x64 each (16 KB)

  const int t = threadIdx.x;
  const int w = t >> 6, l = t & 63;
  const int wm = w >> 2, wn = w & 3;          // 2 m-waves x 4 n-waves
  const int lr = l & 15, lg = l >> 4;
  const int r7 = lr & 7;

  const int bid = blockIdx.x;                 // 256 blocks; XCD = bid & 7
  const int m0 = (bid >> 3) * 256;
  const int n0 = (bid & 7) * 128;

  const unsigned short* gA  = Xb  + (size_t)m0 * K;
  const unsigned short* gB0 = Wqb + (size_t)n0 * K;
  const unsigned short* gB1 = Wkb + (size_t)n0 * K;
  const unsigned short* gB2 = Wvb + (size_t)n0 * K;

  // A: 256x64 = 2048 chunks (4/thread); B per mat: 128x64 = 1024 chunks
  // (2/thread). 8 chunks/row; source pre-swizzled chunk ^= row&7.
  int sarow[4], saoff[4];
#pragma unroll
  for (int i = 0; i < 4; i++) {
    const int c = i * 512 + t;
    sarow[i] = c >> 3;
    saoff[i] = ((c & 7) ^ (sarow[i] & 7)) * 8;
  }
  int sbrow[2], sboff[2];
#pragma unroll
  for (int i = 0; i < 2; i++) {
    const int c = i * 512 + t;
    sbrow[i] = c >> 3;
    sboff[i] = ((c & 7) ^ (sbrow[i] & 7)) * 8;
  }

#define STAGE(s, k0)                                                          \
  do {                                                                        \
    _Pragma("unroll")                                                         \
    for (int i = 0; i < 4; i++)                                               \
      gl_lds16(gA + (size_t)sarow[i] * K + (k0) + saoff[i],                   \
               sAp(s) + (i * 512 + t) * 8);                                   \
    _Pragma("unroll")                                                         \
    for (int i = 0; i < 2; i++) {                                             \
      const size_t gob = (size_t)sbrow[i] * K + (k0) + sboff[i];              \
      const int dl = (i * 512 + t) * 8;                                       \
      gl_lds16(gB0 + gob, sBp(s, 0) + dl);                                    \
      gl_lds16(gB1 + gob, sBp(s, 1) + dl);                                    \
      gl_lds16(gB2 + gob, sBp(s, 2) + dl);                                    \
    }                                                                         \
  } while (0)

  STAGE(0, 0);                                // prologue

  f32x4 acc[3][8][2] = {};                    // [mat][mi][n] = 192 VGPR

#pragma unroll 2
  for (int T = 0; T < 16; ++T) {
    __syncthreads();                          // drains stage(T); frees buf[T^1]
    if (T + 1 < 16) STAGE((T + 1) & 1, (T + 1) * 64);   // lands during compute(T)

    const unsigned short* At = sAp(T & 1);
#pragma unroll
    for (int ks = 0; ks < 2; ++ks) {
      const int swk = (((ks * 4 + lg) ^ r7) << 3);
      bf16x8 afr[8];
#pragma unroll
      for (int mi = 0; mi < 8; ++mi)
        afr[mi] = *reinterpret_cast<const bf16x8*>(
            &At[(wm * 128 + mi * 16 + lr) * 64 + swk]);
#pragma unroll
      for (int mat = 0; mat < 3; ++mat) {
        const unsigned short* Bt = sBp(T & 1, mat);
        bf16x8 bfr[2];
#pragma unroll
        for (int n = 0; n < 2; ++n)
          bfr[n] = *reinterpret_cast<const bf16x8*>(
              &Bt[(wn * 32 + n * 16 + lr) * 64 + swk]);
#pragma unroll
        for (int mi = 0; mi < 8; ++mi)
#pragma unroll
          for (int n = 0; n < 2; ++n)
            acc[mat][mi][n] = mfma16(afr[mi], bfr[n], acc[mat][mi][n]);
      }
    }
  }
#undef STAGE

  // -------- epilogue --------
  __syncthreads();                            // all LDS reads of tile 15 done

  // V: bias, cast, KEY-PERMUTED stores
#pragma unroll
  for (int n = 0; n < 2; ++n) {
    const int col = n0 + wn * 32 + n * 16 + lr;
    const int h = col >> 6, dk = col & 63;
    const float bvv = bv[col];
#pragma unroll
    for (int mi = 0; mi < 8; ++mi) {
      const int row0 = m0 + wm * 128 + mi * 16 + lg * 4;   // 4 consecutive tokens
      const int b = row0 >> 11, s0 = row0 & 2047;
      const int grp = s0 & ~63;
      const int pos = grp + (s0 & 15) * 4 + ((s0 >> 4) & 3);
      unsigned short* vp = &Vto[(((size_t)b * H_ + h) * DK_ + dk) * S_ + pos];
      vp[0]  = bfbits(acc[2][mi][n][0] + bvv);
      vp[4]  = bfbits(acc[2][mi][n][1] + bvv);
      vp[8]  = bfbits(acc[2][mi][n][2] + bvv);
      vp[12] = bfbits(acc[2][mi][n][3] + bvv);
    }
  }

  // Q then K: bounce through LDS (256 x 132 u16), coalesced drain.
  unsigned short* bounce = smem;
  for (int mat = 0; mat < 2; ++mat) {
    const float* bias = mat ? bk : bq;
#pragma unroll
    for (int n = 0; n < 2; ++n) {
      const int col = n0 + wn * 32 + n * 16 + lr;
      const int lcol = wn * 32 + n * 16 + lr;
      const float bs = bias[col];
#pragma unroll
      for (int mi = 0; mi < 8; ++mi) {
#pragma unroll
        for (int r = 0; r < 4; ++r) {
          const int lrow = wm * 128 + mi * 16 + lg * 4 + r;
          float v = acc[mat][mi][n][r] + bs;
          if (mat) v *= 0.18033688011112042f * rw[m0 + lrow];
          bounce[lrow * 132 + lcol] = bfbits(v);
        }
      }
    }
    __syncthreads();
#pragma unroll
    for (int i = 0; i < 4; ++i) {
      const int idx = i * 512 + t;
      const int lrow = idx >> 3, c16 = (idx & 7) * 16;
      const int row = m0 + lrow;
      const int b = row >> 11, s = row & 2047;
      const int col = n0 + c16;
      const int h = col >> 6, dk = col & 63;
      const unsigned short* srcp = &bounce[lrow * 132 + c16];
      unsigned short* dst = (mat ? Ko : Qo) + (((size_t)b * H_ + h) * S_ + s) * DK_ + dk;
#pragma unroll
      for (int j = 0; j < 4; ++j)
        reinterpret_cast<ushort4*>(dst)[j] =
            reinterpret_cast<const ushort4*>(srcp)[j];
    }
    if (mat == 0) __syncthreads();            // bounce reuse; no trailing barrier
  }
#undef sAp
#undef sBp
}

// ---------------------------------------------------------------- flash attention
// Round-23 version: 8 waves x 16 q-rows, paired q-blocks {p,15-p}, KV=64
// prefetch-dbuf, exp2-domain scores (rw baked in K), no running max,
// key-permuted P (one ds_write_b64 per row), denominator via MFMA-with-ones,
// XOR-swizzled K/V/P, XCD-aware 1D grid, setprio on MFMA clusters.
__global__ __launch_bounds__(512)
void SAA_attn(const unsigned short* __restrict__ Q,
              const unsigned short* __restrict__ Kb,
              const unsigned short* __restrict__ Vt,
              const int* __restrict__ maskp,
              unsigned short* __restrict__ Cb)
{
  const int L = (blockIdx.x & 7) * 64 + (blockIdx.x >> 3);
  const int pairid = L & 7;
  const int h = (L >> 3) & 15;
  const int b = L >> 7;

  const int t = threadIdx.x, w = t >> 6, l = t & 63;
  const int lr = l & 15, lg = l >> 4;
  const int mask = maskp[0];

  __shared__ __attribute__((aligned(16))) unsigned short Kt[2][64 * 64];
  __shared__ __attribute__((aligned(16))) unsigned short Vl[2][64 * 64];
  __shared__ __attribute__((aligned(16))) unsigned short Pl[8][16 * 64];

  const size_t bh = (size_t)b * H_ + h;
  const unsigned short* Qbh = Q + bh * S_ * DK_;
  const unsigned short* Kbh = Kb + bh * S_ * DK_;
  const unsigned short* Vbh = Vt + bh * DK_ * S_;
  unsigned short* Pw = &Pl[w][0];

  const int r0 = t >> 3, cc0 = t & 7;
  const int sw0 = (cc0 ^ (r0 & 7)) * 8;

  bf16x8 ones;
#pragma unroll
  for (int i = 0; i < 8; ++i) ones[i] = (__bf16)1.0f;

  for (int half = 0; half < 2; ++half) {
    const int qb = half ? (15 - pairid) : pairid;
    const int q0 = qb * 128;
    const int wq = q0 + w * 16;

    bf16x8 qf[2];
#pragma unroll
    for (int ks = 0; ks < 2; ks++)
      qf[ks] = *reinterpret_cast<const bf16x8*>(
          &Qbh[(size_t)(wq + lr) * DK_ + ks * 32 + lg * 8]);

    f32x4 acc[4] = {};
    f32x4 accs = {};                          // denominator via MFMA-ones

    const int nkt = mask ? (qb * 2 + 2) : (S_ / 64);
    const int wqmax = wq + 15;

    __syncthreads();

    gl_lds16(Kbh + (size_t)r0 * DK_ + sw0, &Kt[0][t * 8]);
    gl_lds16(Vbh + (size_t)r0 * S_ + sw0,  &Vl[0][t * 8]);
    int cur = 0;

    for (int kt = 0; kt < nkt; ++kt) {
      __syncthreads();
      if (kt + 1 < nkt) {
        const int kn = (kt + 1) * 64;
        const int nb = cur ^ 1;
        gl_lds16(Kbh + (size_t)(kn + r0) * DK_ + sw0, &Kt[nb][t * 8]);
        gl_lds16(Vbh + (size_t)r0 * S_ + kn + sw0,    &Vl[nb][t * 8]);
      }

      const int k0 = kt * 64;
      const bool active = (!mask) || (k0 <= wqmax);
      if (active) {
        const unsigned short* Kc = &Kt[cur][0];
        const unsigned short* Vc = &Vl[cur][0];

        __builtin_amdgcn_s_setprio(1);
        f32x4 sc[4] = {};
#pragma unroll
        for (int ks = 0; ks < 2; ++ks) {
          const int swk = (((ks * 4 + lg) ^ (lr & 7)) << 3);
#pragma unroll
          for (int t2 = 0; t2 < 4; ++t2) {
            bf16x8 kf = *reinterpret_cast<const bf16x8*>(&Kc[(t2 * 16 + lr) * 64 + swk]);
            sc[t2] = mfma16(qf[ks], kf, sc[t2]);
          }
        }
        __builtin_amdgcn_s_setprio(0);

        const bool needmask = mask && (k0 + 63 > wq);

#pragma unroll
        for (int r = 0; r < 4; r++) {
          const int row = wq + lg * 4 + r;
          float v0 = sc[0][r], v1 = sc[1][r];
          float v2 = sc[2][r], v3 = sc[3][r];
          if (needmask) {
            if (k0 + lr      > row) v0 = -1e30f;
            if (k0 + 16 + lr > row) v1 = -1e30f;
            if (k0 + 32 + lr > row) v2 = -1e30f;
            if (k0 + 48 + lr > row) v3 = -1e30f;
          }
          const float p0 = __builtin_amdgcn_exp2f(v0);
          const float p1 = __builtin_amdgcn_exp2f(v1);
          const float p2 = __builtin_amdgcn_exp2f(v2);
          const float p3 = __builtin_amdgcn_exp2f(v3);
          const int prow = lg * 4 + r;
          ushort4 pq;
          pq.x = bfbits(p0); pq.y = bfbits(p1);
          pq.z = bfbits(p2); pq.w = bfbits(p3);
          *reinterpret_cast<ushort4*>(
              &Pw[prow * 64 + (((lr >> 1) ^ (prow & 7)) << 3) + ((lr & 1) << 2)]) = pq;
        }

        __builtin_amdgcn_s_setprio(1);
#pragma unroll
        for (int ks = 0; ks < 2; ++ks) {
          const int swk = (((ks * 4 + lg) ^ (lr & 7)) << 3);
          bf16x8 pf = *reinterpret_cast<const bf16x8*>(&Pw[lr * 64 + swk]);
          accs = mfma16(pf, ones, accs);      // row-sum of P (denominator)
#pragma unroll
          for (int dt = 0; dt < 4; ++dt) {
            bf16x8 vf = *reinterpret_cast<const bf16x8*>(&Vc[(dt * 16 + lr) * 64 + swk]);
            acc[dt] = mfma16(pf, vf, acc[dt]);
          }
        }
        __builtin_amdgcn_s_setprio(0);
      }
      cur ^= 1;
    }

    // epilogue: denominator already fully reduced by MFMA (all cols equal)
    float lrun[4];
#pragma unroll
    for (int r = 0; r < 4; r++)
      lrun[r] = __builtin_amdgcn_rcpf(accs[r]);
#pragma unroll
    for (int dt = 0; dt < 4; dt++) {
#pragma unroll
      for (int r = 0; r < 4; r++) {
        const int row = wq + lg * 4 + r;
        const int col = h * DK_ + dt * 16 + lr;
        Cb[((size_t)b * S_ + row) * D_ + col] = bfbits(acc[dt][r] * lrun[r]);
      }
    }
  }
}

// ---------------------------------------------------------------- output GEMM
// Round-15 version: M=512 x N=64, BK=64, prefetch-dbuf, XCD-aware 1D grid.
__global__ __launch_bounds__(512)
void SAA_gemm_out(const unsigned short* __restrict__ Cb,
                  const unsigned short* __restrict__ Wob,
                  const float* __restrict__ bo,
                  float* __restrict__ Y)
{
  const int K = D_;
  __shared__ __attribute__((aligned(16))) unsigned short lA[2][512 * 64];  // 128 KB
  __shared__ __attribute__((aligned(16))) unsigned short lB[2][64 * 64];   // 16 KB

  const int L = (blockIdx.x & 7) * 32 + (blockIdx.x >> 3);
  const int nx = L & 15, my = L >> 4;

  const int t = threadIdx.x;
  const int w = t >> 6, l = t & 63;
  const int lr = l & 15, lg = l >> 4;
  const int r7 = lr & 7;

  const int m0 = my * 512;
  const int n0 = nx * 64;

  const unsigned short* gA = Cb + (size_t)m0 * K;
  const unsigned short* gB = Wob + (size_t)n0 * K;

  const int sr = t >> 3;
  const int soff = ((t & 7) ^ (sr & 7)) * 8;

#define STAGEO(s, k0)                                                         \
  do {                                                                        \
    _Pragma("unroll")                                                         \
    for (int i = 0; i < 8; i++)                                               \
      gl_lds16(gA + (size_t)(i * 64 + sr) * K + (k0) + soff,                  \
               &lA[s][(i * 512 + t) * 8]);                                    \
    gl_lds16(gB + (size_t)sr * K + (k0) + soff, &lB[s][t * 8]);               \
  } while (0)

  STAGEO(0, 0);

  f32x4 acc[4][4] = {};

#pragma unroll 2
  for (int T = 0; T < 16; ++T) {
    __syncthreads();
    if (T + 1 < 16) STAGEO((T + 1) & 1, (T + 1) * 64);

    const unsigned short* At = lA[T & 1];
    const unsigned short* Bt = lB[T & 1];
#pragma unroll
    for (int ks = 0; ks < 2; ks++) {
      const int swk = (((ks * 4 + lg) ^ r7) << 3);
      bf16x8 af[4], bfr[4];
#pragma unroll
      for (int i = 0; i < 4; i++)
        af[i] = *reinterpret_cast<const bf16x8*>(&At[(w * 64 + i * 16 + lr) * 64 + swk]);
#pragma unroll
      for (int j = 0; j < 4; j++)
        bfr[j] = *reinterpret_cast<const bf16x8*>(&Bt[(j * 16 + lr) * 64 + swk]);
#pragma unroll
      for (int i = 0; i < 4; i++)
#pragma unroll
        for (int j = 0; j < 4; j++)
          acc[i][j] = mfma16(af[i], bfr[j], acc[i][j]);
    }
  }
#undef STAGEO

#pragma unroll
  for (int j = 0; j < 4; j++) {
    const int col = n0 + j * 16 + lr;
    const float bsv = bo[col];
#pragma unroll
    for (int i = 0; i < 4; i++) {
#pragma unroll
      for (int r = 0; r < 4; r++) {
        const int row = m0 + w * 64 + i * 16 + lg * 4 + r;
        Y[(size_t)row * D_ + col] = acc[i][j][r] + bsv;
      }
    }
  }
}

// ---------------------------------------------------------------- launch
extern "C" void kernel_launch(void* const* d_in, const int* in_sizes, int n_in,
                              void* d_out, int out_size, void* d_ws, size_t ws_size,
                              hipStream_t stream) {
  const float* input = (const float*)d_in[0];
  const float* rw    = (const float*)d_in[1];
  const int*   maskp = (const int*)d_in[2];
  const float* Wq = (const float*)d_in[3];
  const float* bq = (const float*)d_in[4];
  const float* Wk = (const float*)d_in[5];
  const float* bk = (const float*)d_in[6];
  const float* Wv = (const float*)d_in[7];
  const float* bv = (const float*)d_in[8];
  const float* Wo = (const float*)d_in[9];
  const float* bo = (const float*)d_in[10];

  char* ws = (char*)d_ws;
  unsigned short* Xb  = (unsigned short*)(ws);                 // 16 MB (reused as Cb)
  unsigned short* Wqb = (unsigned short*)(ws + (16u << 20));   // 2 MB each
  unsigned short* Wkb = (unsigned short*)(ws + (18u << 20));
  unsigned short* Wvb = (unsigned short*)(ws + (20u << 20));
  unsigned short* Wob = (unsigned short*)(ws + (22u << 20));
  unsigned short* Qo  = (unsigned short*)(ws + (24u << 20));   // 16 MB
  unsigned short* Ko  = (unsigned short*)(ws + (40u << 20));   // 16 MB
  unsigned short* Vto = (unsigned short*)(ws + (56u << 20));   // 16 MB
  unsigned short* Cb  = Xb;   // Xb dead after QKV GEMM

  SAA_cast_all<<<dim3(512, 5), 256, 0, stream>>>(input, Wq, Wk, Wv, Wo,
                                                 Xb, Wqb, Wkb, Wvb, Wob);

  SAA_gemm_qkv<<<256, 512, 0, stream>>>(Xb, Wqb, Wkb, Wvb, bq, bk, bv, rw,
                                        Qo, Ko, Vto);
  SAA_attn<<<512, 512, 0, stream>>>(Qo, Ko, Vto, maskp, Cb);
  SAA_gemm_out<<<256, 512, 0, stream>>>(Cb, Wob, bo, (float*)d_out);
}

// Round 25
// 151.612 us; speedup vs baseline: 1.6073x; 1.6073x over previous
//
#include <hip/hip_runtime.h>
#include <math.h>

// Problem constants
#define B_  4
#define S_  2048
#define D_  1024
#define H_  16
#define DK_ 64

typedef __bf16 bf16x8 __attribute__((ext_vector_type(8)));
typedef float  f32x4  __attribute__((ext_vector_type(4)));

__device__ __forceinline__ unsigned short f2bf(float f) {
  unsigned int u = __builtin_bit_cast(unsigned int, f);
  u += 0x7fffu + ((u >> 16) & 1u);   // round to nearest even
  return (unsigned short)(u >> 16);
}

__device__ __forceinline__ unsigned short bfbits(float f) {
  __bf16 h = (__bf16)f;              // native cvt (RNE)
  return __builtin_bit_cast(unsigned short, h);
}

__device__ __forceinline__ f32x4 mfma16(bf16x8 a, bf16x8 b, f32x4 c) {
  return __builtin_amdgcn_mfma_f32_16x16x32_bf16(a, b, c, 0, 0, 0);
}

__device__ __forceinline__ void gl_lds16(const unsigned short* g, unsigned short* l) {
  __builtin_amdgcn_global_load_lds(
      (const __attribute__((address_space(1))) void*)g,
      (__attribute__((address_space(3))) void*)l, 16, 0, 0);
}

// ---------------------------------------------------------------- casts (one launch)
__global__ void SAA_cast_all(const float* __restrict__ x,
                             const float* __restrict__ s1, const float* __restrict__ s2,
                             const float* __restrict__ s3, const float* __restrict__ s4,
                             unsigned short* __restrict__ dx,
                             unsigned short* __restrict__ d1, unsigned short* __restrict__ d2,
                             unsigned short* __restrict__ d3, unsigned short* __restrict__ d4)
{
  const int y = blockIdx.y;
  const float* src = (y == 0) ? x : (y == 1) ? s1 : (y == 2) ? s2 : (y == 3) ? s3 : s4;
  unsigned short* dst = (y == 0) ? dx : (y == 1) ? d1 : (y == 2) ? d2 : (y == 3) ? d3 : d4;
  const int n4 = (y == 0) ? (B_ * S_ * D_) / 4 : (D_ * D_) / 4;
  int i = blockIdx.x * blockDim.x + threadIdx.x;
  int stride = gridDim.x * blockDim.x;
  for (; i < n4; i += stride) {
    float4 v = reinterpret_cast<const float4*>(src)[i];
    ushort4 o;
    o.x = f2bf(v.x); o.y = f2bf(v.y); o.z = f2bf(v.z); o.w = f2bf(v.w);
    reinterpret_cast<ushort4*>(dst)[i] = o;
  }
}

// ---------------------------------------------------------------- fused QKV GEMM
// ROUND-23 PROVEN VERSION (56 us, ~930 TF): BM=256, BK=32, all-bf16 staging,
// 104 B/MFMA, prefetch-dbuf, chunk-XOR swizzle (chunk ^= (row>>1)&3, 0
// conflicts), XCD-aware grid (n0 = bid&7). Round-24's BK=64/160KB variant
// spilled (compiler capped VGPR at 128; acc needs 192) -- reverted.
// K rows pre-scaled by 0.125*log2(e)*rw[s] (scores leave QK^T in exp2-domain).
// V stored KEY-PERMUTED (token s -> (s&~63) + (s&15)*4 + ((s>>4)&3)); the
// attention P layout matches, making the softmax P-store one ds_write_b64.
__global__ __launch_bounds__(512)
void SAA_gemm_qkv(const unsigned short* __restrict__ Xb,
                  const unsigned short* __restrict__ Wqb,
                  const unsigned short* __restrict__ Wkb,
                  const unsigned short* __restrict__ Wvb,
                  const float* __restrict__ bq,
                  const float* __restrict__ bk,
                  const float* __restrict__ bv,
                  const float* __restrict__ rw,
                  unsigned short* __restrict__ Qo,
                  unsigned short* __restrict__ Ko,
                  unsigned short* __restrict__ Vto)
{
  const int K = D_;
  __shared__ __attribute__((aligned(16))) unsigned short smem[40960];   // 80 KB
#define sAp(sl)     (smem + (sl) * 8192)                      // 256x32 each
#define sBp(sl, m)  (smem + 16384 + ((sl) * 3 + (m)) * 4096)  // 128x32 each

  const int t = threadIdx.x;
  const int w = t >> 6, l = t & 63;
  const int wm = w >> 2, wn = w & 3;          // 2 m-waves x 4 n-waves
  const int lr = l & 15, lg = l >> 4;

  const int bid = blockIdx.x;                 // 256 blocks; XCD = bid & 7
  const int m0 = (bid >> 3) * 256;
  const int n0 = (bid & 7) * 128;

  const unsigned short* gA  = Xb  + (size_t)m0 * K;
  const unsigned short* gB0 = Wqb + (size_t)n0 * K;
  const unsigned short* gB1 = Wkb + (size_t)n0 * K;
  const unsigned short* gB2 = Wvb + (size_t)n0 * K;

  int sarow[2], saoff[2];
#pragma unroll
  for (int i = 0; i < 2; i++) {
    const int c = i * 512 + t;
    sarow[i] = c >> 2;
    saoff[i] = ((c & 3) ^ ((sarow[i] >> 1) & 3)) * 8;
  }
  const int sbrow = t >> 2;
  const int sboff = ((t & 3) ^ ((sbrow >> 1) & 3)) * 8;

#define STAGE(s, k0)                                                          \
  do {                                                                        \
    _Pragma("unroll")                                                         \
    for (int i = 0; i < 2; i++)                                               \
      gl_lds16(gA + (size_t)sarow[i] * K + (k0) + saoff[i],                   \
               sAp(s) + (i * 512 + t) * 8);                                   \
    const size_t gob = (size_t)sbrow * K + (k0) + sboff;                      \
    gl_lds16(gB0 + gob, sBp(s, 0) + t * 8);                                   \
    gl_lds16(gB1 + gob, sBp(s, 1) + t * 8);                                   \
    gl_lds16(gB2 + gob, sBp(s, 2) + t * 8);                                   \
  } while (0)

  STAGE(0, 0);                                // prologue

  f32x4 acc[3][8][2] = {};                    // [mat][mi][n] = 192 VGPR

#pragma unroll 2
  for (int T = 0; T < 32; ++T) {
    __syncthreads();                          // drains stage(T); frees buf[T^1]
    if (T + 1 < 32) STAGE((T + 1) & 1, (T + 1) * 32);   // lands during compute(T)

    const unsigned short* At = sAp(T & 1);
    bf16x8 afr[8];
#pragma unroll
    for (int mi = 0; mi < 8; ++mi) {
      const int row = wm * 128 + mi * 16 + lr;
      afr[mi] = *reinterpret_cast<const bf16x8*>(
          &At[row * 32 + ((lg ^ ((row >> 1) & 3)) << 3)]);
    }
#pragma unroll
    for (int mat = 0; mat < 3; ++mat) {
      const unsigned short* Bt = sBp(T & 1, mat);
      bf16x8 bfr[2];
#pragma unroll
      for (int n = 0; n < 2; ++n) {
        const int row = wn * 32 + n * 16 + lr;
        bfr[n] = *reinterpret_cast<const bf16x8*>(
            &Bt[row * 32 + ((lg ^ ((row >> 1) & 3)) << 3)]);
      }
#pragma unroll
      for (int mi = 0; mi < 8; ++mi)
#pragma unroll
        for (int n = 0; n < 2; ++n)
          acc[mat][mi][n] = mfma16(afr[mi], bfr[n], acc[mat][mi][n]);
    }
  }
#undef STAGE

  // -------- epilogue --------
  __syncthreads();                            // all LDS reads of tile 31 done

  // V: bias, cast, KEY-PERMUTED stores
#pragma unroll
  for (int n = 0; n < 2; ++n) {
    const int col = n0 + wn * 32 + n * 16 + lr;
    const int h = col >> 6, dk = col & 63;
    const float bvv = bv[col];
#pragma unroll
    for (int mi = 0; mi < 8; ++mi) {
      const int row0 = m0 + wm * 128 + mi * 16 + lg * 4;   // 4 consecutive tokens
      const int b = row0 >> 11, s0 = row0 & 2047;
      const int grp = s0 & ~63;
      const int pos = grp + (s0 & 15) * 4 + ((s0 >> 4) & 3);
      unsigned short* vp = &Vto[(((size_t)b * H_ + h) * DK_ + dk) * S_ + pos];
      vp[0]  = bfbits(acc[2][mi][n][0] + bvv);
      vp[4]  = bfbits(acc[2][mi][n][1] + bvv);
      vp[8]  = bfbits(acc[2][mi][n][2] + bvv);
      vp[12] = bfbits(acc[2][mi][n][3] + bvv);
    }
  }

  // Q then K: bounce through LDS (256 x 132 u16), coalesced drain.
  unsigned short* bounce = smem;
  for (int mat = 0; mat < 2; ++mat) {
    const float* bias = mat ? bk : bq;
#pragma unroll
    for (int n = 0; n < 2; ++n) {
      const int col = n0 + wn * 32 + n * 16 + lr;
      const int lcol = wn * 32 + n * 16 + lr;
      const float bs = bias[col];
#pragma unroll
      for (int mi = 0; mi < 8; ++mi) {
#pragma unroll
        for (int r = 0; r < 4; ++r) {
          const int lrow = wm * 128 + mi * 16 + lg * 4 + r;
          float v = acc[mat][mi][n][r] + bs;
          if (mat) v *= 0.18033688011112042f * rw[m0 + lrow];
          bounce[lrow * 132 + lcol] = bfbits(v);
        }
      }
    }
    __syncthreads();
#pragma unroll
    for (int i = 0; i < 4; ++i) {
      const int idx = i * 512 + t;
      const int lrow = idx >> 3, c16 = (idx & 7) * 16;
      const int row = m0 + lrow;
      const int b = row >> 11, s = row & 2047;
      const int col = n0 + c16;
      const int h = col >> 6, dk = col & 63;
      const unsigned short* srcp = &bounce[lrow * 132 + c16];
      unsigned short* dst = (mat ? Ko : Qo) + (((size_t)b * H_ + h) * S_ + s) * DK_ + dk;
#pragma unroll
      for (int j = 0; j < 4; ++j)
        reinterpret_cast<ushort4*>(dst)[j] =
            reinterpret_cast<const ushort4*>(srcp)[j];
    }
    __syncthreads();
  }
#undef sAp
#undef sBp
}

// ---------------------------------------------------------------- flash attention
// Round-23 version: 8 waves x 16 q-rows, paired q-blocks {p,15-p}, KV=64
// prefetch-dbuf, exp2-domain scores (rw baked in K), no running max,
// key-permuted P (one ds_write_b64 per row), denominator via MFMA-with-ones,
// XOR-swizzled K/V/P, XCD-aware 1D grid, setprio on MFMA clusters.
__global__ __launch_bounds__(512)
void SAA_attn(const unsigned short* __restrict__ Q,
              const unsigned short* __restrict__ Kb,
              const unsigned short* __restrict__ Vt,
              const int* __restrict__ maskp,
              unsigned short* __restrict__ Cb)
{
  const int L = (blockIdx.x & 7) * 64 + (blockIdx.x >> 3);
  const int pairid = L & 7;
  const int h = (L >> 3) & 15;
  const int b = L >> 7;

  const int t = threadIdx.x, w = t >> 6, l = t & 63;
  const int lr = l & 15, lg = l >> 4;
  const int mask = maskp[0];

  __shared__ __attribute__((aligned(16))) unsigned short Kt[2][64 * 64];
  __shared__ __attribute__((aligned(16))) unsigned short Vl[2][64 * 64];
  __shared__ __attribute__((aligned(16))) unsigned short Pl[8][16 * 64];

  const size_t bh = (size_t)b * H_ + h;
  const unsigned short* Qbh = Q + bh * S_ * DK_;
  const unsigned short* Kbh = Kb + bh * S_ * DK_;
  const unsigned short* Vbh = Vt + bh * DK_ * S_;
  unsigned short* Pw = &Pl[w][0];

  const int r0 = t >> 3, cc0 = t & 7;
  const int sw0 = (cc0 ^ (r0 & 7)) * 8;

  bf16x8 ones;
#pragma unroll
  for (int i = 0; i < 8; ++i) ones[i] = (__bf16)1.0f;

  for (int half = 0; half < 2; ++half) {
    const int qb = half ? (15 - pairid) : pairid;
    const int q0 = qb * 128;
    const int wq = q0 + w * 16;

    bf16x8 qf[2];
#pragma unroll
    for (int ks = 0; ks < 2; ks++)
      qf[ks] = *reinterpret_cast<const bf16x8*>(
          &Qbh[(size_t)(wq + lr) * DK_ + ks * 32 + lg * 8]);

    f32x4 acc[4] = {};
    f32x4 accs = {};                          // denominator via MFMA-ones

    const int nkt = mask ? (qb * 2 + 2) : (S_ / 64);
    const int wqmax = wq + 15;

    __syncthreads();

    gl_lds16(Kbh + (size_t)r0 * DK_ + sw0, &Kt[0][t * 8]);
    gl_lds16(Vbh + (size_t)r0 * S_ + sw0,  &Vl[0][t * 8]);
    int cur = 0;

    for (int kt = 0; kt < nkt; ++kt) {
      __syncthreads();
      if (kt + 1 < nkt) {
        const int kn = (kt + 1) * 64;
        const int nb = cur ^ 1;
        gl_lds16(Kbh + (size_t)(kn + r0) * DK_ + sw0, &Kt[nb][t * 8]);
        gl_lds16(Vbh + (size_t)r0 * S_ + kn + sw0,    &Vl[nb][t * 8]);
      }

      const int k0 = kt * 64;
      const bool active = (!mask) || (k0 <= wqmax);
      if (active) {
        const unsigned short* Kc = &Kt[cur][0];
        const unsigned short* Vc = &Vl[cur][0];

        __builtin_amdgcn_s_setprio(1);
        f32x4 sc[4] = {};
#pragma unroll
        for (int ks = 0; ks < 2; ++ks) {
          const int swk = (((ks * 4 + lg) ^ (lr & 7)) << 3);
#pragma unroll
          for (int t2 = 0; t2 < 4; ++t2) {
            bf16x8 kf = *reinterpret_cast<const bf16x8*>(&Kc[(t2 * 16 + lr) * 64 + swk]);
            sc[t2] = mfma16(qf[ks], kf, sc[t2]);
          }
        }
        __builtin_amdgcn_s_setprio(0);

        const bool needmask = mask && (k0 + 63 > wq);

#pragma unroll
        for (int r = 0; r < 4; r++) {
          const int row = wq + lg * 4 + r;
          float v0 = sc[0][r], v1 = sc[1][r];
          float v2 = sc[2][r], v3 = sc[3][r];
          if (needmask) {
            if (k0 + lr      > row) v0 = -1e30f;
            if (k0 + 16 + lr > row) v1 = -1e30f;
            if (k0 + 32 + lr > row) v2 = -1e30f;
            if (k0 + 48 + lr > row) v3 = -1e30f;
          }
          const float p0 = __builtin_amdgcn_exp2f(v0);
          const float p1 = __builtin_amdgcn_exp2f(v1);
          const float p2 = __builtin_amdgcn_exp2f(v2);
          const float p3 = __builtin_amdgcn_exp2f(v3);
          const int prow = lg * 4 + r;
          ushort4 pq;
          pq.x = bfbits(p0); pq.y = bfbits(p1);
          pq.z = bfbits(p2); pq.w = bfbits(p3);
          *reinterpret_cast<ushort4*>(
              &Pw[prow * 64 + (((lr >> 1) ^ (prow & 7)) << 3) + ((lr & 1) << 2)]) = pq;
        }

        __builtin_amdgcn_s_setprio(1);
#pragma unroll
        for (int ks = 0; ks < 2; ++ks) {
          const int swk = (((ks * 4 + lg) ^ (lr & 7)) << 3);
          bf16x8 pf = *reinterpret_cast<const bf16x8*>(&Pw[lr * 64 + swk]);
          accs = mfma16(pf, ones, accs);      // row-sum of P (denominator)
#pragma unroll
          for (int dt = 0; dt < 4; ++dt) {
            bf16x8 vf = *reinterpret_cast<const bf16x8*>(&Vc[(dt * 16 + lr) * 64 + swk]);
            acc[dt] = mfma16(pf, vf, acc[dt]);
          }
        }
        __builtin_amdgcn_s_setprio(0);
      }
      cur ^= 1;
    }

    // epilogue: denominator already fully reduced by MFMA (all cols equal)
    float lrun[4];
#pragma unroll
    for (int r = 0; r < 4; r++)
      lrun[r] = __builtin_amdgcn_rcpf(accs[r]);
#pragma unroll
    for (int dt = 0; dt < 4; dt++) {
#pragma unroll
      for (int r = 0; r < 4; r++) {
        const int row = wq + lg * 4 + r;
        const int col = h * DK_ + dt * 16 + lr;
        Cb[((size_t)b * S_ + row) * D_ + col] = bfbits(acc[dt][r] * lrun[r]);
      }
    }
  }
}

// ---------------------------------------------------------------- output GEMM
// Round-15 version: M=512 x N=64, BK=64, prefetch-dbuf, XCD-aware 1D grid.
__global__ __launch_bounds__(512)
void SAA_gemm_out(const unsigned short* __restrict__ Cb,
                  const unsigned short* __restrict__ Wob,
                  const float* __restrict__ bo,
                  float* __restrict__ Y)
{
  const int K = D_;
  __shared__ __attribute__((aligned(16))) unsigned short lA[2][512 * 64];  // 128 KB
  __shared__ __attribute__((aligned(16))) unsigned short lB[2][64 * 64];   // 16 KB

  const int L = (blockIdx.x & 7) * 32 + (blockIdx.x >> 3);
  const int nx = L & 15, my = L >> 4;

  const int t = threadIdx.x;
  const int w = t >> 6, l = t & 63;
  const int lr = l & 15, lg = l >> 4;
  const int r7 = lr & 7;

  const int m0 = my * 512;
  const int n0 = nx * 64;

  const unsigned short* gA = Cb + (size_t)m0 * K;
  const unsigned short* gB = Wob + (size_t)n0 * K;

  const int sr = t >> 3;
  const int soff = ((t & 7) ^ (sr & 7)) * 8;

#define STAGEO(s, k0)                                                         \
  do {                                                                        \
    _Pragma("unroll")                                                         \
    for (int i = 0; i < 8; i++)                                               \
      gl_lds16(gA + (size_t)(i * 64 + sr) * K + (k0) + soff,                  \
               &lA[s][(i * 512 + t) * 8]);                                    \
    gl_lds16(gB + (size_t)sr * K + (k0) + soff, &lB[s][t * 8]);               \
  } while (0)

  STAGEO(0, 0);

  f32x4 acc[4][4] = {};

#pragma unroll 2
  for (int T = 0; T < 16; ++T) {
    __syncthreads();
    if (T + 1 < 16) STAGEO((T + 1) & 1, (T + 1) * 64);

    const unsigned short* At = lA[T & 1];
    const unsigned short* Bt = lB[T & 1];
#pragma unroll
    for (int ks = 0; ks < 2; ks++) {
      const int swk = (((ks * 4 + lg) ^ r7) << 3);
      bf16x8 af[4], bfr[4];
#pragma unroll
      for (int i = 0; i < 4; i++)
        af[i] = *reinterpret_cast<const bf16x8*>(&At[(w * 64 + i * 16 + lr) * 64 + swk]);
#pragma unroll
      for (int j = 0; j < 4; j++)
        bfr[j] = *reinterpret_cast<const bf16x8*>(&Bt[(j * 16 + lr) * 64 + swk]);
#pragma unroll
      for (int i = 0; i < 4; i++)
#pragma unroll
        for (int j = 0; j < 4; j++)
          acc[i][j] = mfma16(af[i], bfr[j], acc[i][j]);
    }
  }
#undef STAGEO

#pragma unroll
  for (int j = 0; j < 4; j++) {
    const int col = n0 + j * 16 + lr;
    const float bsv = bo[col];
#pragma unroll
    for (int i = 0; i < 4; i++) {
#pragma unroll
      for (int r = 0; r < 4; r++) {
        const int row = m0 + w * 64 + i * 16 + lg * 4 + r;
        Y[(size_t)row * D_ + col] = acc[i][j][r] + bsv;
      }
    }
  }
}

// ---------------------------------------------------------------- launch
extern "C" void kernel_launch(void* const* d_in, const int* in_sizes, int n_in,
                              void* d_out, int out_size, void* d_ws, size_t ws_size,
                              hipStream_t stream) {
  const float* input = (const float*)d_in[0];
  const float* rw    = (const float*)d_in[1];
  const int*   maskp = (const int*)d_in[2];
  const float* Wq = (const float*)d_in[3];
  const float* bq = (const float*)d_in[4];
  const float* Wk = (const float*)d_in[5];
  const float* bk = (const float*)d_in[6];
  const float* Wv = (const float*)d_in[7];
  const float* bv = (const float*)d_in[8];
  const float* Wo = (const float*)d_in[9];
  const float* bo = (const float*)d_in[10];

  char* ws = (char*)d_ws;
  unsigned short* Xb  = (unsigned short*)(ws);                 // 16 MB (reused as Cb)
  unsigned short* Wqb = (unsigned short*)(ws + (16u << 20));   // 2 MB each
  unsigned short* Wkb = (unsigned short*)(ws + (18u << 20));
  unsigned short* Wvb = (unsigned short*)(ws + (20u << 20));
  unsigned short* Wob = (unsigned short*)(ws + (22u << 20));
  unsigned short* Qo  = (unsigned short*)(ws + (24u << 20));   // 16 MB
  unsigned short* Ko  = (unsigned short*)(ws + (40u << 20));   // 16 MB
  unsigned short* Vto = (unsigned short*)(ws + (56u << 20));   // 16 MB
  unsigned short* Cb  = Xb;   // Xb dead after QKV GEMM

  SAA_cast_all<<<dim3(512, 5), 256, 0, stream>>>(input, Wq, Wk, Wv, Wo,
                                                 Xb, Wqb, Wkb, Wvb, Wob);

  SAA_gemm_qkv<<<256, 512, 0, stream>>>(Xb, Wqb, Wkb, Wvb, bq, bk, bv, rw,
                                        Qo, Ko, Vto);
  SAA_attn<<<512, 512, 0, stream>>>(Qo, Ko, Vto, maskp, Cb);
  SAA_gemm_out<<<256, 512, 0, stream>>>(Cb, Wob, bo, (float*)d_out);
}